// Round 1
// baseline (100.186 us; speedup 1.0000x reference)
//
#include <hip/hip_runtime.h>
#include <math.h>

// MS_QCR, split design.
//
// Key fact: the 5-qubit circuit U depends only on reservoir_weights, and the
// initial state is a REAL product state supported on the bit2=0 subspace
// (wire-2 angle is 0). Hence
//     out[b] = psi0(b)^T A psi0(b) + readout_b,   A = Re(U^H diag(coef) U)|16x16
// and since psi_p psi_q factorizes per wire with m(s) in {c^2, c*s, s^2},
// the whole quantum part is an 81-coefficient multilinear polynomial in
// {1, cos a_w, sin a_w} for the 4 data wires (a = f0,f1,g0,g1).
//
// Kernel A (1 block, once per call): evolve the 16 basis states with the
// previously-verified gate code, build A, collapse to the 81-tensor, change
// basis to {1,cos,sin}, fold readout_b, write D[81] into d_ws.
// Kernel B (per row): conv frontends -> 4 angles -> 4 sincos -> 80-FMA
// contraction. ~5x fewer VALU ops than the in-thread statevector sim.

__global__ __launch_bounds__(256) void qcr_prep(
    const float* __restrict__ rw, const float* __restrict__ readout_w,
    const float* __restrict__ readout_b, float* __restrict__ Dout)
{
    __shared__ float s_rxc[15], s_rxs[15], s_ryc[15], s_rys[15];
    __shared__ float s_zzc[96], s_zzs[96], s_coef[32];
    __shared__ float phir[16][33], phii[16][33];   // stride 33: conflict-free q-reads
    __shared__ float sA[16][16];
    __shared__ float sC[81];

    const int tid = threadIdx.x;

    // ---- gate tables (identical to the verified single-kernel version) ----
    if (tid < 15) {
        const int l = tid / 5, i = tid % 5;
        const float tx = rw[l*25 + i*5 + 0] * 0.5f;
        const float ty = rw[l*25 + i*5 + 1] * 0.5f;
        s_rxc[tid] = cosf(tx); s_rxs[tid] = sinf(tx);
        s_ryc[tid] = cosf(ty); s_rys[tid] = sinf(ty);
    }
    if (tid >= 32 && tid < 128) {
        const int e = tid - 32;
        const int l = e >> 5, bi = e & 31;
        float ang = 0.f;
        for (int i = 0; i < 5; ++i) {
            const float si = ((bi >> (4 - i)) & 1) ? -1.f : 1.f;
            for (int j = i + 1; j < 5; ++j) {
                const float sj = ((bi >> (4 - j)) & 1) ? -1.f : 1.f;
                ang += rw[l*25 + i*5 + j] * si * sj;
            }
        }
        ang *= -0.5f;
        s_zzc[e] = cosf(ang); s_zzs[e] = sinf(ang);
    }
    if (tid >= 128 && tid < 160) {
        const int bi = tid - 128;
        float c = 0.f;
        for (int w = 0; w < 5; ++w) {
            const float sw = ((bi >> (4 - w)) & 1) ? -1.f : 1.f;
            c += readout_w[w] * sw;
        }
        s_coef[bi] = c;
    }
    __syncthreads();

    // ---- evolve the 16 basis states of the bit2=0 subspace (lane p = p0p1p3p4) ----
    if (tid < 16) {
        float ar[32], ai[32];
        const int P = ((tid & 12) << 1) | (tid & 3);   // insert bit2=0
        #pragma unroll
        for (int idx = 0; idx < 32; ++idx) { ar[idx] = (idx == P) ? 1.f : 0.f; ai[idx] = 0.f; }

        for (int l = 0; l < 3; ++l) {
            #pragma unroll
            for (int qb = 0; qb < 5; ++qb) {
                const float rc = s_rxc[l*5 + qb], rs = s_rxs[l*5 + qb];
                const float yc = s_ryc[l*5 + qb], ys = s_rys[l*5 + qb];
                const int str = 1 << (4 - qb);
                #pragma unroll
                for (int g = 0; g < 16; ++g) {
                    const int i0 = ((g & ~(str - 1)) << 1) | (g & (str - 1));
                    const int i1 = i0 | str;
                    const float a0r = ar[i0], a0i = ai[i0];
                    const float a1r = ar[i1], a1i = ai[i1];
                    const float n0r =  rc*a0r + rs*a1i;
                    const float n0i =  rc*a0i - rs*a1r;
                    const float n1r =  rs*a0i + rc*a1r;
                    const float n1i = -rs*a0r + rc*a1i;
                    ar[i0] = yc*n0r - ys*n1r;
                    ai[i0] = yc*n0i - ys*n1i;
                    ar[i1] = ys*n0r + yc*n1r;
                    ai[i1] = ys*n0i + yc*n1i;
                }
            }
            #pragma unroll
            for (int idx = 0; idx < 32; ++idx) {
                const float pc = s_zzc[l*32 + idx], ps = s_zzs[l*32 + idx];
                const float r = ar[idx]*pc - ai[idx]*ps;
                ai[idx]       = ar[idx]*ps + ai[idx]*pc;
                ar[idx]       = r;
            }
        }
        #pragma unroll
        for (int k = 0; k < 32; ++k) { phir[tid][k] = ar[k]; phii[tid][k] = ai[k]; }
    }
    __syncthreads();

    // ---- A_pq = Re <phi_p| diag(coef) |phi_q>  (real since coef real) ----
    {
        const int p = tid >> 4, q = tid & 15;
        float acc = 0.f;
        #pragma unroll
        for (int k = 0; k < 32; ++k)
            acc += s_coef[k] * (phir[p][k]*phir[q][k] + phii[p][k]*phii[q][k]);
        sA[p][q] = acc;
    }
    __syncthreads();

    // ---- collapse to 81-tensor C[j0,j1,j3,j4], j = p_w + q_w in {0,1,2} ----
    if (tid < 81) {
        const int j0 = tid / 27, j1 = (tid / 9) % 3, j3 = (tid / 3) % 3, j4 = tid % 3;
        const int n0 = 1 + (j0 == 1), n1 = 1 + (j1 == 1);
        const int n3 = 1 + (j3 == 1), n4 = 1 + (j4 == 1);
        float s = 0.f;
        for (int a0 = 0; a0 < n0; ++a0) {
            const int pb0 = (j0 == 2) ? 1 : ((j0 == 1) ? a0 : 0);
            const int qb0 = (j0 == 0) ? 0 : ((j0 == 1) ? 1 - a0 : 1);
            for (int a1 = 0; a1 < n1; ++a1) {
                const int pb1 = (j1 == 2) ? 1 : ((j1 == 1) ? a1 : 0);
                const int qb1 = (j1 == 0) ? 0 : ((j1 == 1) ? 1 - a1 : 1);
                for (int a3 = 0; a3 < n3; ++a3) {
                    const int pb3 = (j3 == 2) ? 1 : ((j3 == 1) ? a3 : 0);
                    const int qb3 = (j3 == 0) ? 0 : ((j3 == 1) ? 1 - a3 : 1);
                    for (int a4 = 0; a4 < n4; ++a4) {
                        const int pb4 = (j4 == 2) ? 1 : ((j4 == 1) ? a4 : 0);
                        const int qb4 = (j4 == 0) ? 0 : ((j4 == 1) ? 1 - a4 : 1);
                        s += sA[(pb0<<3)|(pb1<<2)|(pb3<<1)|pb4]
                               [(qb0<<3)|(qb1<<2)|(qb3<<1)|qb4];
                    }
                }
            }
        }
        sC[tid] = s;
    }
    __syncthreads();

    // ---- per-wire basis change {c^2, cs, s^2} -> {1, cosA, sinA} ----
    // m(0)=(1+C)/2, m(1)=S/2, m(2)=(1-C)/2 :
    //   new[0]=(v0+v2)/2 (const), new[1]=(v0-v2)/2 (C), new[2]=v1/2 (S)
    #pragma unroll
    for (int pass = 0; pass < 4; ++pass) {
        const int P  = (pass == 0) ? 27 : (pass == 1) ? 9 : (pass == 2) ? 3 : 1;
        const int O1 = (pass == 0) ? 9  : 27;
        const int O2 = (pass <= 1) ? 3  : 9;
        const int O3 = (pass <= 2) ? 1  : 3;
        if (tid < 27) {
            const int base = (tid / 9) * O1 + ((tid / 3) % 3) * O2 + (tid % 3) * O3;
            const float v0 = sC[base], v1 = sC[base + P], v2 = sC[base + 2*P];
            sC[base]       = 0.5f * (v0 + v2);
            sC[base + P]   = 0.5f * (v0 - v2);
            sC[base + 2*P] = 0.5f * v1;
        }
        __syncthreads();
    }

    if (tid == 0) sC[0] += readout_b[0];     // basis element (1,1,1,1)
    __syncthreads();
    if (tid < 81) Dout[tid] = sC[tid];
}

__global__ __launch_bounds__(256) void qcr_main(
    const float* __restrict__ x_short, const float* __restrict__ x_long,
    const float* __restrict__ conv_s_w, const float* __restrict__ conv_s_b,
    const float* __restrict__ lin_s_w,  const float* __restrict__ lin_s_b,
    const float* __restrict__ conv_l_w, const float* __restrict__ conv_l_b,
    const float* __restrict__ lin_l_w,  const float* __restrict__ lin_l_b,
    const float* __restrict__ D, float* __restrict__ out, int nb)
{
    const int b = blockIdx.x * 256 + threadIdx.x;
    if (b >= nb) return;

    // ---------------- classical: short branch ----------------
    float xs[5];
    #pragma unroll
    for (int p = 0; p < 5; ++p) xs[p] = x_short[b*5 + p];

    float f0 = lin_s_b[0], f1 = lin_s_b[1];
    #pragma unroll
    for (int c = 0; c < 4; ++c) {
        #pragma unroll
        for (int p = 0; p < 5; ++p) {
            float h = conv_s_b[c];
            #pragma unroll
            for (int k = 0; k < 3; ++k) {
                const int q = p - 1 + k;             // pad (1,1)
                if (q >= 0 && q < 5) h += conv_s_w[c*3 + k] * xs[q];
            }
            h = fmaxf(h, 0.f);
            f0 += lin_s_w[      c*5 + p] * h;
            f1 += lin_s_w[20 + c*5 + p] * h;
        }
    }

    // ---------------- classical: long branch ----------------
    float xl[20];
    {   // (b*20*4)B offset is 16B-aligned -> float4 loads
        const float4* xl4 = reinterpret_cast<const float4*>(x_long + b*20);
        #pragma unroll
        for (int v = 0; v < 5; ++v) {
            const float4 t = xl4[v];
            xl[4*v+0] = t.x; xl[4*v+1] = t.y; xl[4*v+2] = t.z; xl[4*v+3] = t.w;
        }
    }

    float g0 = lin_l_b[0], g1 = lin_l_b[1];
    #pragma unroll
    for (int c = 0; c < 4; ++c) {
        #pragma unroll
        for (int q = 0; q < 10; ++q) {
            float hm = 0.f;                          // relu(max(a,b)) = max(max(a,b),0)
            #pragma unroll
            for (int t = 0; t < 2; ++t) {
                const int p = 2*q + t;
                float h = conv_l_b[c];
                #pragma unroll
                for (int k = 0; k < 5; ++k) {
                    const int u = p - 2 + k;         // pad (2,2)
                    if (u >= 0 && u < 20) h += conv_l_w[c*5 + k] * xl[u];
                }
                hm = fmaxf(hm, h);
            }
            g0 += lin_l_w[      c*10 + q] * hm;
            g1 += lin_l_w[40 + c*10 + q] * hm;
        }
    }

    // ---------------- quantum readout: 81-term multilinear form ----------------
    // wires: 0 <- f0, 1 <- f1, 3 <- g0, 4 <- g1; flat k = ((k0*3+k1)*3+k3)*3+k4
    float C0, S0, C1, S1, C3, S3, C4, S4;
    sincosf(f0, &S0, &C0);
    sincosf(f1, &S1, &C1);
    sincosf(g0, &S3, &C3);
    sincosf(g1, &S4, &C4);

    float t4[27];
    #pragma unroll
    for (int j = 0; j < 27; ++j)
        t4[j] = D[3*j] + C4 * D[3*j + 1] + S4 * D[3*j + 2];
    float t3[9];
    #pragma unroll
    for (int j = 0; j < 9; ++j)
        t3[j] = t4[3*j] + C3 * t4[3*j + 1] + S3 * t4[3*j + 2];
    float t1[3];
    #pragma unroll
    for (int j = 0; j < 3; ++j)
        t1[j] = t3[3*j] + C1 * t3[3*j + 1] + S1 * t3[3*j + 2];

    out[b] = t1[0] + C0 * t1[1] + S0 * t1[2];   // readout_b already folded into D[0]
}

extern "C" void kernel_launch(void* const* d_in, const int* in_sizes, int n_in,
                              void* d_out, int out_size, void* d_ws, size_t ws_size,
                              hipStream_t stream) {
    const float* x_short    = (const float*)d_in[0];
    const float* x_long     = (const float*)d_in[1];
    const float* conv_s_w   = (const float*)d_in[2];
    const float* conv_s_b   = (const float*)d_in[3];
    const float* lin_s_w    = (const float*)d_in[4];
    const float* lin_s_b    = (const float*)d_in[5];
    const float* conv_l_w   = (const float*)d_in[6];
    const float* conv_l_b   = (const float*)d_in[7];
    const float* lin_l_w    = (const float*)d_in[8];
    const float* lin_l_b    = (const float*)d_in[9];
    const float* rw         = (const float*)d_in[10];
    const float* readout_w  = (const float*)d_in[11];
    const float* readout_b  = (const float*)d_in[12];
    float* out = (float*)d_out;
    float* Dws = (float*)d_ws;

    const int nb = in_sizes[0] / 5;

    hipLaunchKernelGGL(qcr_prep, dim3(1), dim3(256), 0, stream,
                       rw, readout_w, readout_b, Dws);
    hipLaunchKernelGGL(qcr_main, dim3((nb + 255) / 256), dim3(256), 0, stream,
                       x_short, x_long, conv_s_w, conv_s_b, lin_s_w, lin_s_b,
                       conv_l_w, conv_l_b, lin_l_w, lin_l_b, Dws, out, nb);
}

// Round 2
// 95.832 us; speedup vs baseline: 1.0454x; 1.0454x over previous
//
#include <hip/hip_runtime.h>
#include <math.h>

// MS_QCR, fully fused single-launch design.
//
// out[b] = psi0(b)^T A psi0(b) + readout_b with A = Re(U^H diag(coef) U)|16x16,
// collapsed to an 81-coefficient multilinear polynomial D in
// {1, cos a_w, sin a_w} over the 4 data wires (a = f0,f1,g0,g1).
//
// This version computes D *per block* (weight-only, redundant but cheap) so
// everything is ONE kernel launch and D lives in LDS:
//  - basis evolution parallelized over all 256 threads: 16 states x 32 amps
//    = 512 complex amps, 2 per thread (amps t and t+16 of state tid>>4).
//    Butterfly partners for qubits 1..4 are lane^stride within a 16-lane
//    group -> __shfl_xor, no barriers. Qubit 0 pairs (t, t+16) thread-local.
//  - A/collapse/basis-change epilogue identical to the verified split version.
//  - row phase reads D[81] straight from LDS (uniform -> broadcast reads).

__global__ __launch_bounds__(256) void qcr_fused(
    const float* __restrict__ x_short, const float* __restrict__ x_long,
    const float* __restrict__ conv_s_w, const float* __restrict__ conv_s_b,
    const float* __restrict__ lin_s_w,  const float* __restrict__ lin_s_b,
    const float* __restrict__ conv_l_w, const float* __restrict__ conv_l_b,
    const float* __restrict__ lin_l_w,  const float* __restrict__ lin_l_b,
    const float* __restrict__ rw,       const float* __restrict__ readout_w,
    const float* __restrict__ readout_b, float* __restrict__ out, int nb)
{
    __shared__ float s_rxc[15], s_rxs[15], s_ryc[15], s_rys[15];
    __shared__ float s_zzc[96], s_zzs[96], s_coef[32];
    __shared__ float phir[16][33], phii[16][33];
    __shared__ float sA[16][16];
    __shared__ float sC[81];

    const int tid = threadIdx.x;

    // ---- gate tables (weight-only; same as verified version) ----
    if (tid < 15) {
        const int l = tid / 5, i = tid % 5;
        const float tx = rw[l*25 + i*5 + 0] * 0.5f;
        const float ty = rw[l*25 + i*5 + 1] * 0.5f;
        s_rxc[tid] = cosf(tx); s_rxs[tid] = sinf(tx);
        s_ryc[tid] = cosf(ty); s_rys[tid] = sinf(ty);
    }
    if (tid >= 32 && tid < 128) {
        const int e = tid - 32;
        const int l = e >> 5, bi = e & 31;
        float ang = 0.f;
        for (int i = 0; i < 5; ++i) {
            const float si = ((bi >> (4 - i)) & 1) ? -1.f : 1.f;
            for (int j = i + 1; j < 5; ++j) {
                const float sj = ((bi >> (4 - j)) & 1) ? -1.f : 1.f;
                ang += rw[l*25 + i*5 + j] * si * sj;
            }
        }
        ang *= -0.5f;
        s_zzc[e] = cosf(ang); s_zzs[e] = sinf(ang);
    }
    if (tid >= 128 && tid < 160) {
        const int bi = tid - 128;
        float c = 0.f;
        for (int w = 0; w < 5; ++w) {
            const float sw = ((bi >> (4 - w)) & 1) ? -1.f : 1.f;
            c += readout_w[w] * sw;
        }
        s_coef[bi] = c;
    }
    __syncthreads();

    // ---- basis evolution: 256 threads, 2 amps each, shfl butterflies ----
    {
        const int p = tid >> 4;            // state index (bit2=0 subspace)
        const int t = tid & 15;            // owns amps t (lo) and t+16 (hi)
        const int P = ((p & 12) << 1) | (p & 3);   // insert bit2=0

        float lr = (t == P)      ? 1.f : 0.f, li = 0.f;
        float hr = (t + 16 == P) ? 1.f : 0.f, hi2 = 0.f;

        for (int l = 0; l < 3; ++l) {
            #pragma unroll
            for (int qb = 0; qb < 5; ++qb) {
                const float rc = s_rxc[l*5 + qb], rs = s_rxs[l*5 + qb];
                const float yc = s_ryc[l*5 + qb], ys = s_rys[l*5 + qb];
                if (qb == 0) {
                    // stride 16: pair (t, t+16) is thread-local; lo is a0.
                    const float n0r =  rc*lr  + rs*hi2;
                    const float n0i =  rc*li  - rs*hr;
                    const float n1r =  rs*li  + rc*hr;
                    const float n1i = -rs*lr  + rc*hi2;
                    lr  = yc*n0r - ys*n1r;  li  = yc*n0i - ys*n1i;
                    hr  = ys*n0r + yc*n1r;  hi2 = ys*n0i + yc*n1i;
                } else {
                    const int str = 1 << (4 - qb);        // 8,4,2,1
                    const bool up = (t & str) != 0;       // holds a1 role
                    // lo amp (index t): partner amp t^str = partner's lo
                    float pr = __shfl_xor(lr, str, 64);
                    float pi = __shfl_xor(li, str, 64);
                    {
                        const float a0r = up ? pr : lr,  a0i = up ? pi : li;
                        const float a1r = up ? lr : pr,  a1i = up ? li : pi;
                        const float n0r =  rc*a0r + rs*a1i;
                        const float n0i =  rc*a0i - rs*a1r;
                        const float n1r =  rs*a0i + rc*a1r;
                        const float n1i = -rs*a0r + rc*a1i;
                        lr = up ? (ys*n0r + yc*n1r) : (yc*n0r - ys*n1r);
                        li = up ? (ys*n0i + yc*n1i) : (yc*n0i - ys*n1i);
                    }
                    // hi amp (index t+16): partner amp (t^str)+16 = partner's hi
                    pr = __shfl_xor(hr,  str, 64);
                    pi = __shfl_xor(hi2, str, 64);
                    {
                        const float a0r = up ? pr : hr,  a0i = up ? pi : hi2;
                        const float a1r = up ? hr : pr,  a1i = up ? hi2 : pi;
                        const float n0r =  rc*a0r + rs*a1i;
                        const float n0i =  rc*a0i - rs*a1r;
                        const float n1r =  rs*a0i + rc*a1r;
                        const float n1i = -rs*a0r + rc*a1i;
                        hr  = up ? (ys*n0r + yc*n1r) : (yc*n0r - ys*n1r);
                        hi2 = up ? (ys*n0i + yc*n1i) : (yc*n0i - ys*n1i);
                    }
                }
            }
            // ZZ phases: diagonal in basis index
            {
                float pc = s_zzc[l*32 + t], ps = s_zzs[l*32 + t];
                float r  = lr*pc - li*ps;  li = lr*ps + li*pc;  lr = r;
                pc = s_zzc[l*32 + t + 16]; ps = s_zzs[l*32 + t + 16];
                r  = hr*pc - hi2*ps;  hi2 = hr*ps + hi2*pc;  hr = r;
            }
        }
        phir[p][t]      = lr;  phii[p][t]      = li;
        phir[p][t + 16] = hr;  phii[p][t + 16] = hi2;
    }
    __syncthreads();

    // ---- A_pq = Re <phi_p| diag(coef) |phi_q> (real since coef real) ----
    {
        const int p = tid >> 4, q = tid & 15;
        float acc = 0.f;
        #pragma unroll
        for (int k = 0; k < 32; ++k)
            acc += s_coef[k] * (phir[p][k]*phir[q][k] + phii[p][k]*phii[q][k]);
        sA[p][q] = acc;
    }
    __syncthreads();

    // ---- collapse to 81-tensor C[j0,j1,j3,j4], j = p_w + q_w in {0,1,2} ----
    if (tid < 81) {
        const int j0 = tid / 27, j1 = (tid / 9) % 3, j3 = (tid / 3) % 3, j4 = tid % 3;
        const int n0 = 1 + (j0 == 1), n1 = 1 + (j1 == 1);
        const int n3 = 1 + (j3 == 1), n4 = 1 + (j4 == 1);
        float s = 0.f;
        for (int a0 = 0; a0 < n0; ++a0) {
            const int pb0 = (j0 == 2) ? 1 : ((j0 == 1) ? a0 : 0);
            const int qb0 = (j0 == 0) ? 0 : ((j0 == 1) ? 1 - a0 : 1);
            for (int a1 = 0; a1 < n1; ++a1) {
                const int pb1 = (j1 == 2) ? 1 : ((j1 == 1) ? a1 : 0);
                const int qb1 = (j1 == 0) ? 0 : ((j1 == 1) ? 1 - a1 : 1);
                for (int a3 = 0; a3 < n3; ++a3) {
                    const int pb3 = (j3 == 2) ? 1 : ((j3 == 1) ? a3 : 0);
                    const int qb3 = (j3 == 0) ? 0 : ((j3 == 1) ? 1 - a3 : 1);
                    for (int a4 = 0; a4 < n4; ++a4) {
                        const int pb4 = (j4 == 2) ? 1 : ((j4 == 1) ? a4 : 0);
                        const int qb4 = (j4 == 0) ? 0 : ((j4 == 1) ? 1 - a4 : 1);
                        s += sA[(pb0<<3)|(pb1<<2)|(pb3<<1)|pb4]
                               [(qb0<<3)|(qb1<<2)|(qb3<<1)|qb4];
                    }
                }
            }
        }
        sC[tid] = s;
    }
    __syncthreads();

    // ---- per-wire basis change {c^2, cs, s^2} -> {1, cosA, sinA} ----
    #pragma unroll
    for (int pass = 0; pass < 4; ++pass) {
        const int P  = (pass == 0) ? 27 : (pass == 1) ? 9 : (pass == 2) ? 3 : 1;
        const int O1 = (pass == 0) ? 9  : 27;
        const int O2 = (pass <= 1) ? 3  : 9;
        const int O3 = (pass <= 2) ? 1  : 3;
        if (tid < 27) {
            const int base = (tid / 9) * O1 + ((tid / 3) % 3) * O2 + (tid % 3) * O3;
            const float v0 = sC[base], v1 = sC[base + P], v2 = sC[base + 2*P];
            sC[base]       = 0.5f * (v0 + v2);
            sC[base + P]   = 0.5f * (v0 - v2);
            sC[base + 2*P] = 0.5f * v1;
        }
        __syncthreads();
    }
    if (tid == 0) sC[0] += readout_b[0];     // basis element (1,1,1,1)
    __syncthreads();

    // =================== per-row phase (no more barriers) ===================
    const int b = blockIdx.x * 256 + tid;
    if (b >= nb) return;

    // ---------------- classical: short branch ----------------
    float xs[5];
    #pragma unroll
    for (int p = 0; p < 5; ++p) xs[p] = x_short[b*5 + p];

    float f0 = lin_s_b[0], f1 = lin_s_b[1];
    #pragma unroll
    for (int c = 0; c < 4; ++c) {
        #pragma unroll
        for (int p = 0; p < 5; ++p) {
            float h = conv_s_b[c];
            #pragma unroll
            for (int k = 0; k < 3; ++k) {
                const int q = p - 1 + k;             // pad (1,1)
                if (q >= 0 && q < 5) h += conv_s_w[c*3 + k] * xs[q];
            }
            h = fmaxf(h, 0.f);
            f0 += lin_s_w[      c*5 + p] * h;
            f1 += lin_s_w[20 + c*5 + p] * h;
        }
    }

    // ---------------- classical: long branch ----------------
    float xl[20];
    {   // (b*20*4)B offset is 16B-aligned -> float4 loads
        const float4* xl4 = reinterpret_cast<const float4*>(x_long + b*20);
        #pragma unroll
        for (int v = 0; v < 5; ++v) {
            const float4 t = xl4[v];
            xl[4*v+0] = t.x; xl[4*v+1] = t.y; xl[4*v+2] = t.z; xl[4*v+3] = t.w;
        }
    }

    float g0 = lin_l_b[0], g1 = lin_l_b[1];
    #pragma unroll
    for (int c = 0; c < 4; ++c) {
        #pragma unroll
        for (int q = 0; q < 10; ++q) {
            float hm = 0.f;                          // relu(max(a,b)) = max(max(a,b),0)
            #pragma unroll
            for (int t = 0; t < 2; ++t) {
                const int p = 2*q + t;
                float h = conv_l_b[c];
                #pragma unroll
                for (int k = 0; k < 5; ++k) {
                    const int u = p - 2 + k;         // pad (2,2)
                    if (u >= 0 && u < 20) h += conv_l_w[c*5 + k] * xl[u];
                }
                hm = fmaxf(hm, h);
            }
            g0 += lin_l_w[      c*10 + q] * hm;
            g1 += lin_l_w[40 + c*10 + q] * hm;
        }
    }

    // ---------------- quantum readout: 81-term multilinear form ----------------
    float C0, S0, C1, S1, C3, S3, C4, S4;
    sincosf(f0, &S0, &C0);
    sincosf(f1, &S1, &C1);
    sincosf(g0, &S3, &C3);
    sincosf(g1, &S4, &C4);

    float t4[27];
    #pragma unroll
    for (int j = 0; j < 27; ++j)
        t4[j] = sC[3*j] + C4 * sC[3*j + 1] + S4 * sC[3*j + 2];
    float t3[9];
    #pragma unroll
    for (int j = 0; j < 9; ++j)
        t3[j] = t4[3*j] + C3 * t4[3*j + 1] + S3 * t4[3*j + 2];
    float t1[3];
    #pragma unroll
    for (int j = 0; j < 3; ++j)
        t1[j] = t3[3*j] + C1 * t3[3*j + 1] + S1 * t3[3*j + 2];

    out[b] = t1[0] + C0 * t1[1] + S0 * t1[2];   // readout_b folded into sC[0]
}

extern "C" void kernel_launch(void* const* d_in, const int* in_sizes, int n_in,
                              void* d_out, int out_size, void* d_ws, size_t ws_size,
                              hipStream_t stream) {
    const float* x_short    = (const float*)d_in[0];
    const float* x_long     = (const float*)d_in[1];
    const float* conv_s_w   = (const float*)d_in[2];
    const float* conv_s_b   = (const float*)d_in[3];
    const float* lin_s_w    = (const float*)d_in[4];
    const float* lin_s_b    = (const float*)d_in[5];
    const float* conv_l_w   = (const float*)d_in[6];
    const float* conv_l_b   = (const float*)d_in[7];
    const float* lin_l_w    = (const float*)d_in[8];
    const float* lin_l_b    = (const float*)d_in[9];
    const float* rw         = (const float*)d_in[10];
    const float* readout_w  = (const float*)d_in[11];
    const float* readout_b  = (const float*)d_in[12];
    float* out = (float*)d_out;

    const int nb = in_sizes[0] / 5;
    dim3 grid((nb + 255) / 256), block(256);
    hipLaunchKernelGGL(qcr_fused, grid, block, 0, stream,
                       x_short, x_long, conv_s_w, conv_s_b, lin_s_w, lin_s_b,
                       conv_l_w, conv_l_b, lin_l_w, lin_l_b, rw, readout_w,
                       readout_b, out, nb);
}